// Round 9
// baseline (913.505 us; speedup 1.0000x reference)
//
#include <hip/hip_runtime.h>
#include <stdint.h>

typedef unsigned short u16;
typedef unsigned int u32;
typedef float f32x4 __attribute__((ext_vector_type(4)));
typedef __bf16 bf16x8 __attribute__((ext_vector_type(8)));
typedef u16 u16x8 __attribute__((ext_vector_type(8)));
typedef u16 u16x4 __attribute__((ext_vector_type(4)));

// Problem geometry (fixed)
#define NB   4
#define SEQ  2048
#define EMB  1024
#define NH   16
#define HDIM 64

#define QSCALE 0.18033688011112042f   // log2(e)/8, folded into qp at projection

__device__ __forceinline__ f32x4 mfma16(bf16x8 a, bf16x8 b, f32x4 c) {
  return __builtin_amdgcn_mfma_f32_16x16x32_bf16(a, b, c, 0, 0, 0);
}
__device__ __forceinline__ u16 f2bf(float f) {
  u32 u = __builtin_bit_cast(u32, f);
  u += 0x7FFFu + ((u >> 16) & 1u);      // round-to-nearest-even
  return (u16)(u >> 16);
}
__device__ __forceinline__ u32 pk2bf(float lo, float hi) {
  return (u32)f2bf(lo) | ((u32)f2bf(hi) << 16);
}
__device__ __forceinline__ float bf2f(u16 h) {
  return __builtin_bit_cast(float, (u32)h << 16);
}
__device__ __forceinline__ bf16x8 ldg8(const u16* p) {
  return *reinterpret_cast<const bf16x8*>(p);
}

// ---------------- prep: fp32->bf16 cvt (y=0..5) + mask bitpack (y=6) ----------------
__global__ __launch_bounds__(256) void prep_kernel(
    const float* __restrict__ q, const float* __restrict__ k, const float* __restrict__ v,
    const float* __restrict__ Wk, const float* __restrict__ Wv, const float* __restrict__ Wo,
    const int* __restrict__ mask,
    u16* __restrict__ qb, u16* __restrict__ kb, u16* __restrict__ vb,
    u16* __restrict__ Wkb, u16* __restrict__ Wvb, u16* __restrict__ Wob,
    u32* __restrict__ bits) {
  const int y = blockIdx.y;
  if (y == 6) {
    const int idx = blockIdx.x * 256 + threadIdx.x;
    if (idx >= NB * SEQ * 64) return;
    const int w = idx & 63;
    const size_t rowbase = (size_t)(idx >> 6) * SEQ;
    const int4* p = reinterpret_cast<const int4*>(mask + rowbase + w * 32);
    u32 m = 0;
#pragma unroll
    for (int j = 0; j < 8; ++j) {
      int4 v4 = p[j];
      m |= (v4.x != 0 ? 1u : 0u) << (j * 4 + 0);
      m |= (v4.y != 0 ? 1u : 0u) << (j * 4 + 1);
      m |= (v4.z != 0 ? 1u : 0u) << (j * 4 + 2);
      m |= (v4.w != 0 ? 1u : 0u) << (j * 4 + 3);
    }
    bits[idx] = m;
    return;
  }
  const float* src; u16* dst; int n8;
  switch (y) {
    case 0: src = q;  dst = qb;  n8 = NB * SEQ * EMB / 8; break;
    case 1: src = k;  dst = kb;  n8 = NB * SEQ * EMB / 8; break;
    case 2: src = v;  dst = vb;  n8 = NB * SEQ * EMB / 8; break;
    case 3: src = Wk; dst = Wkb; n8 = EMB * EMB / 8; break;
    case 4: src = Wv; dst = Wvb; n8 = EMB * EMB / 8; break;
    default: src = Wo; dst = Wob; n8 = EMB * EMB / 8; break;
  }
  int i = blockIdx.x * 256 + threadIdx.x;
  if (i >= n8) return;
  const float4* s = reinterpret_cast<const float4*>(src) + (size_t)i * 2;
  float4 a = s[0], b = s[1];
  u16x8 o;
  o[0] = f2bf(a.x); o[1] = f2bf(a.y); o[2] = f2bf(a.z); o[3] = f2bf(a.w);
  o[4] = f2bf(b.x); o[5] = f2bf(b.y); o[6] = f2bf(b.z); o[7] = f2bf(b.w);
  reinterpret_cast<u16x8*>(dst)[i] = o;
}

// per (b, 64-row qtile, 64-col ktile): 1 if fully unmasked
__global__ __launch_bounds__(256) void tileok_kernel(const u32* __restrict__ bits,
                                                     unsigned char* __restrict__ tok) {
  const int idx = blockIdx.x * 256 + threadIdx.x;      // < 4*32*32
  const int b = idx >> 10, qt = (idx >> 5) & 31, kt = idx & 31;
  const u32* bb = bits + (size_t)b * SEQ * 64;
  u32 acc = 0xFFFFFFFFu;
  for (int rr = 0; rr < 64; ++rr) {
    const u32* pr = bb + (size_t)(qt * 64 + rr) * 64 + kt * 2;
    acc &= pr[0] & pr[1];
  }
  tok[idx] = (acc == 0xFFFFFFFFu) ? 1 : 0;
}

// ---------------- 128x128x(K=1024) bf16 GEMM mainloop (m97 structure) ----------------
__device__ __forceinline__ void gemm_tile(const u16* __restrict__ A,
                                          const u16* __restrict__ W,
                                          int brow, int bcol, int tid,
                                          u16* As, u16* Bs, f32x4 acc[4][4]) {
  const int K = 1024;
  const int l = tid & 63, wv = tid >> 6;
  const int lr = l & 15, lg = l >> 4;
  const int wr = wv >> 1, wc = wv & 1;
  const int srow = l >> 3;
  const int skb = (l & 7) * 16;

  for (int k0 = 0; k0 < K; k0 += 64) {
#pragma unroll
    for (int r = 0; r < 4; ++r) {
      const int chunk = r * 4 + wv;
      const int row = chunk * 8 + srow;
      const char* ga = (const char*)A + ((size_t)(brow + row) * K + k0) * 2 + skb;
      const char* gb = (const char*)W + ((size_t)(bcol + row) * K + k0) * 2 + skb;
      __builtin_amdgcn_global_load_lds(
          (const __attribute__((address_space(1))) u32*)ga,
          (__attribute__((address_space(3))) u32*)((char*)As + chunk * 1024), 16, 0, 0);
      __builtin_amdgcn_global_load_lds(
          (const __attribute__((address_space(1))) u32*)gb,
          (__attribute__((address_space(3))) u32*)((char*)Bs + chunk * 1024), 16, 0, 0);
    }
    __syncthreads();
#pragma unroll
    for (int ks = 0; ks < 2; ++ks) {
      bf16x8 af[4], bfr[4];
#pragma unroll
      for (int m = 0; m < 4; ++m)
        af[m] = *reinterpret_cast<const bf16x8*>(
            (const char*)As + (wr * 64 + m * 16 + lr) * 128 + ks * 64 + lg * 16);
#pragma unroll
      for (int n = 0; n < 4; ++n)
        bfr[n] = *reinterpret_cast<const bf16x8*>(
            (const char*)Bs + (wc * 64 + n * 16 + lr) * 128 + ks * 64 + lg * 16);
#pragma unroll
      for (int m = 0; m < 4; ++m)
#pragma unroll
        for (int n = 0; n < 4; ++n)
          acc[m][n] = mfma16(af[m], bfr[n], acc[m][n]);
    }
    __syncthreads();
  }
}

// z=0: qp = (q@Wv^T+bv)*QSCALE  [B][H][S][HD]
// z=1: kp = k@Wk^T+bk           [B][H][S][HD]
// z=2: vpT = v@Wv^T+bv          [B][H][HD][S] (transposed via LDS)
__global__ __launch_bounds__(256) void proj_gemm(
    const u16* __restrict__ qb, const u16* __restrict__ kb, const u16* __restrict__ vb,
    const u16* __restrict__ Wvb, const u16* __restrict__ Wkb,
    const float* __restrict__ bv, const float* __restrict__ bkp,
    u16* __restrict__ qp, u16* __restrict__ kp, u16* __restrict__ vpT) {
  __shared__ __align__(16) u32 smem_u32[8192];
  u16* As = (u16*)smem_u32;
  u16* Bs = As + 128 * 64;
  const int z = blockIdx.z;
  const u16* A = (z == 0) ? qb : (z == 1) ? kb : vb;
  const u16* W = (z == 1) ? Wkb : Wvb;
  const float* bias = (z == 1) ? bkp : bv;
  const int brow = blockIdx.y * 128;
  const int bcol = blockIdx.x * 128;
  const int tid = threadIdx.x;
  f32x4 acc[4][4] = {};
  gemm_tile(A, W, brow, bcol, tid, As, Bs, acc);
  const int l = tid & 63, wv = tid >> 6;
  const int lr = l & 15, lg = l >> 4;
  const int wr = wv >> 1, wc = wv & 1;

  if (z == 2) {
#pragma unroll
    for (int m = 0; m < 4; ++m)
#pragma unroll
      for (int n = 0; n < 4; ++n) {
        const int cl = wc * 64 + n * 16 + lr;
        const float b0 = bias[bcol + cl];
        const u32 w0 = pk2bf(acc[m][n][0] + b0, acc[m][n][1] + b0);
        const u32 w1 = pk2bf(acc[m][n][2] + b0, acc[m][n][3] + b0);
        const int rp0 = wr * 32 + m * 8 + lg * 2;
        const int a32 = cl * 64 + (rp0 ^ ((lr & 7) << 2));
        uint2 wv2; wv2.x = w0; wv2.y = w1;
        *reinterpret_cast<uint2*>(&smem_u32[a32]) = wv2;
      }
    __syncthreads();
#pragma unroll
    for (int i = 0; i < 8; ++i) {
      const int idx = i * 256 + tid;
      const int cl = idx >> 4;
      const int rp0 = (idx & 15) * 4;
      const int a32 = cl * 64 + (rp0 ^ ((cl & 7) << 2));
      const uint4 d = *reinterpret_cast<const uint4*>(&smem_u32[a32]);
      const int col = bcol + cl, hh = col >> 6, hd = col & 63;
      const int row = brow + rp0 * 2, bb = row >> 11, s = row & 2047;
      *reinterpret_cast<uint4*>(
          vpT + ((((size_t)bb * NH + hh) * HDIM + hd) * SEQ + s)) = d;
    }
  } else {
    u16* dst = (z == 0) ? qp : kp;
    const float sc = (z == 0) ? QSCALE : 1.0f;
#pragma unroll
    for (int m = 0; m < 4; ++m)
#pragma unroll
      for (int n = 0; n < 4; ++n)
#pragma unroll
        for (int r = 0; r < 4; ++r) {
          const int row = brow + wr * 64 + m * 16 + lg * 4 + r;
          const int col = bcol + wc * 64 + n * 16 + lr;
          const float vl = (acc[m][n][r] + bias[col]) * sc;
          const int bb = row >> 11, s = row & 2047, hh = col >> 6, hd = col & 63;
          dst[(((size_t)bb * NH + hh) * SEQ + s) * HDIM + hd] = f2bf(vl);
        }
  }
}

__global__ __launch_bounds__(256) void out_gemm(
    const u16* __restrict__ ctxb, const u16* __restrict__ Wob,
    const float* __restrict__ bo, float* __restrict__ outF) {
  __shared__ __align__(16) u32 smem_u32[8192];
  u16* As = (u16*)smem_u32;
  u16* Bs = As + 128 * 64;
  const int brow = blockIdx.y * 128;
  const int bcol = blockIdx.x * 128;
  const int tid = threadIdx.x;
  f32x4 acc[4][4] = {};
  gemm_tile(ctxb, Wob, brow, bcol, tid, As, Bs, acc);
  const int l = tid & 63, wv = tid >> 6;
  const int lr = l & 15, lg = l >> 4;
  const int wr = wv >> 1, wc = wv & 1;
#pragma unroll
  for (int m = 0; m < 4; ++m)
#pragma unroll
    for (int n = 0; n < 4; ++n)
#pragma unroll
      for (int r = 0; r < 4; ++r) {
        const int row = brow + wr * 64 + m * 16 + lg * 4 + r;
        const int col = bcol + wc * 64 + n * 16 + lr;
        outF[(size_t)row * EMB + col] = acc[m][n][r] + bo[col];
      }
}

// ---------------- fused attention: barrier-free two-pass, wave-independent ----------------
// 2048 blocks x 4 waves = 8192 waves; wave = 16 q-rows of one (b,h), FULL K=2048.
// bh = bid & 63 (XCD = bh%8); qt = (bid>>6)*4 + wid.
// Pass 1: QK MFMA -> exp2 -> rowsum (registers only).
// Pass 2 (per 64-col tile): K loads, V loads (both in flight), scores,
//   pn = exp2(s)*rinv -> pbuf (normalized bf16, swizzled), PV MFMA, then
//   VECTORIZED attn store: lane reads 4 bf16 from pbuf, 1x f32x4 PLAIN store
//   (through L2 -- no nontemporal: nt bypassed L2 and throttled at ~2 TB/s).
// NO __syncthreads anywhere; pbuf is wave-private.
__global__ __launch_bounds__(256) void attn_kernel(
    const u16* __restrict__ qp, const u16* __restrict__ kp, const u16* __restrict__ vpT,
    const u32* __restrict__ bits, const unsigned char* __restrict__ tok,
    float* __restrict__ attn, u16* __restrict__ ctxb) {
  __shared__ __align__(16) u16 pbuf[4][16][64];        // wave-private [wid]
  const int tid = threadIdx.x;
  const int l = tid & 63, wid = tid >> 6;
  const int lr = l & 15, lg = l >> 4;
  const int bid = blockIdx.x;
  const int bh_i = bid & 63;
  const int qt = (bid >> 6) * 4 + wid;                 // 0..127
  const int q0 = qt * 16;
  const int h = bh_i & 15, b = bh_i >> 4;
  const size_t bh = (size_t)b * NH + h;
  const u16* qpb = qp + bh * (SEQ * HDIM);
  const u16* kpb = kp + bh * (SEQ * HDIM);
  const u16* vpb = vpT + bh * (HDIM * SEQ);
  float* attb = attn + bh * ((size_t)SEQ * SEQ);
  const unsigned char* tokb = tok + ((size_t)b * 32 + (q0 >> 6)) * 32;
  const u32* bitsb = bits + (size_t)b * SEQ * 64;

  // Q fragments (16 rows): A[i=lr][k=lg*8+j] for the two K=32 slices
  bf16x8 aq[2];
#pragma unroll
  for (int d = 0; d < 2; ++d)
    aq[d] = ldg8(qpb + (size_t)(q0 + lr) * HDIM + d * 32 + lg * 8);

  // ---- pass 1: rowsums only ----
  float sums[4] = {0.f, 0.f, 0.f, 0.f};
  for (int kt = 0; kt < 32; ++kt) {
    const int kc = kt * 64;
    const bool okt = tokb[kt] != 0;
    bf16x8 bk8[4][2];
#pragma unroll
    for (int st = 0; st < 4; ++st)
#pragma unroll
      for (int d = 0; d < 2; ++d)
        bk8[st][d] = ldg8(kpb + (size_t)(kc + st * 16 + lr) * HDIM + d * 32 + lg * 8);
#pragma unroll
    for (int st = 0; st < 4; ++st) {
      f32x4 s = {0.f, 0.f, 0.f, 0.f};
      s = mfma16(aq[0], bk8[st][0], s);
      s = mfma16(aq[1], bk8[st][1], s);
#pragma unroll
      for (int r = 0; r < 4; ++r) {
        float sc = s[r];
        if (!okt) {
          const int qrow = q0 + lg * 4 + r;
          const int kpos = kc + st * 16 + lr;
          const u32 wb = bitsb[(size_t)qrow * 64 + (kpos >> 5)];
          if (!((wb >> (kpos & 31)) & 1u)) sc = -1e30f;
        }
        sums[r] += __builtin_amdgcn_exp2f(sc);
      }
    }
  }
  // reduce over the 16 lr-lanes; every lane ends with rinv for rows lg*4+r
  float rinv[4];
#pragma unroll
  for (int r = 0; r < 4; ++r) {
    float vsum = sums[r];
    vsum += __shfl_xor(vsum, 1);
    vsum += __shfl_xor(vsum, 2);
    vsum += __shfl_xor(vsum, 4);
    vsum += __shfl_xor(vsum, 8);
    rinv[r] = 1.0f / vsum;
  }

  // ---- pass 2: recompute scores, pbuf relayout, PV, vectorized attn store ----
  f32x4 cacc[4] = {};
  for (int kt = 0; kt < 32; ++kt) {
    const int kc = kt * 64;
    const bool okt = tokb[kt] != 0;
    bf16x8 bk8[4][2];
#pragma unroll
    for (int st = 0; st < 4; ++st)
#pragma unroll
      for (int d = 0; d < 2; ++d)
        bk8[st][d] = ldg8(kpb + (size_t)(kc + st * 16 + lr) * HDIM + d * 32 + lg * 8);
    // V loads right behind K so both are in flight before any store
    bf16x8 vf[4][2];
#pragma unroll
    for (int ds = 0; ds < 4; ++ds)
#pragma unroll
      for (int x = 0; x < 2; ++x)
        vf[ds][x] = ldg8(vpb + (size_t)(ds * 16 + lr) * SEQ + kc + x * 32 + lg * 8);
#pragma unroll
    for (int st = 0; st < 4; ++st) {
      f32x4 s = {0.f, 0.f, 0.f, 0.f};
      s = mfma16(aq[0], bk8[st][0], s);
      s = mfma16(aq[1], bk8[st][1], s);
#pragma unroll
      for (int r = 0; r < 4; ++r) {
        float sc = s[r];
        if (!okt) {
          const int qrow = q0 + lg * 4 + r;
          const int kpos = kc + st * 16 + lr;
          const u32 wb = bitsb[(size_t)qrow * 64 + (kpos >> 5)];
          if (!((wb >> (kpos & 31)) & 1u)) sc = -1e30f;
        }
        const float pn = __builtin_amdgcn_exp2f(sc) * rinv[r];
        const int row = lg * 4 + r;
        const int col = st * 16 + lr;
        pbuf[wid][row][col ^ ((row & 7) << 3)] = f2bf(pn);
      }
    }
    // PV: wave-local readback as A-fragments (lgkm wait covers the ds_writes)
#pragma unroll
    for (int ks = 0; ks < 2; ++ks) {
      const int cb = ks * 32 + lg * 8;
      const bf16x8 pa = *reinterpret_cast<const bf16x8*>(
          &pbuf[wid][lr][cb ^ ((lr & 7) << 3)]);
#pragma unroll
      for (int ds = 0; ds < 4; ++ds)
        cacc[ds] = mfma16(pa, vf[ds][ks], cacc[ds]);
    }
    // vectorized attn store: lane -> (row = i*4+lg, 4 cols at (l&15)*4), plain f32x4
#pragma unroll
    for (int i = 0; i < 4; ++i) {
      const int row = i * 4 + lg;
      const int c4 = (l & 15) * 4;
      const u16x4 raw = *reinterpret_cast<const u16x4*>(
          &pbuf[wid][row][c4 ^ ((row & 7) << 3)]);
      f32x4 o;
      o[0] = bf2f(raw[0]); o[1] = bf2f(raw[1]);
      o[2] = bf2f(raw[2]); o[3] = bf2f(raw[3]);
      *reinterpret_cast<f32x4*>(attb + (size_t)(q0 + row) * SEQ + kc + c4) = o;
    }
  }

  // ctx write: rows lg*4+r, d-col ds*16+lr (normalized already)
#pragma unroll
  for (int ds = 0; ds < 4; ++ds)
#pragma unroll
    for (int r = 0; r < 4; ++r)
      ctxb[((size_t)b * SEQ + q0 + lg * 4 + r) * EMB + h * HDIM + ds * 16 + lr] =
          f2bf(cacc[ds][r]);
}

// ---------------- host launch ----------------
extern "C" void kernel_launch(void* const* d_in, const int* in_sizes, int n_in,
                              void* d_out, int out_size, void* d_ws, size_t ws_size,
                              hipStream_t stream) {
  const float* q   = (const float*)d_in[0];
  const float* k   = (const float*)d_in[1];
  const float* v   = (const float*)d_in[2];
  const int* mask  = (const int*)d_in[3];
  const float* Wk  = (const float*)d_in[4];
  const float* bk  = (const float*)d_in[5];
  const float* Wv  = (const float*)d_in[6];
  const float* bv  = (const float*)d_in[7];
  const float* Wo  = (const float*)d_in[8];
  const float* bo  = (const float*)d_in[9];

  float* outF = (float*)d_out;
  float* attnF = outF + (size_t)NB * SEQ * EMB;

  const size_t MiB = 1024 * 1024;
  char* ws = (char*)d_ws;
  u16* qb   = (u16*)(ws + 0 * MiB);
  u16* kb   = (u16*)(ws + 16 * MiB);
  u16* vb   = (u16*)(ws + 32 * MiB);
  u16* Wvb  = (u16*)(ws + 48 * MiB);
  u16* Wkb  = (u16*)(ws + 50 * MiB);
  u16* Wob  = (u16*)(ws + 52 * MiB);
  u16* qpB  = (u16*)(ws + 54 * MiB);
  u16* kpB  = (u16*)(ws + 70 * MiB);
  u16* vpT  = (u16*)(ws + 86 * MiB);
  u16* ctxb = (u16*)(ws + 102 * MiB);
  u32* bits = (u32*)(ws + 118 * MiB);
  unsigned char* tok = (unsigned char*)(ws + 120 * MiB);

  prep_kernel<<<dim3(NB * SEQ * EMB / 8 / 256, 7), 256, 0, stream>>>(
      q, k, v, Wk, Wv, Wo, mask, qb, kb, vb, Wkb, Wvb, Wob, bits);

  tileok_kernel<<<NB * 32 * 32 / 256, 256, 0, stream>>>(bits, tok);

  proj_gemm<<<dim3(EMB / 128, NB * SEQ / 128, 3), 256, 0, stream>>>(
      qb, kb, vb, Wvb, Wkb, bv, bk, qpB, kpB, vpT);

  attn_kernel<<<2048, 256, 0, stream>>>(
      qpB, kpB, vpT, bits, tok, attnF, ctxb);

  out_gemm<<<dim3(EMB / 128, NB * SEQ / 128), 256, 0, stream>>>(ctxb, Wob, bo, outF);
}

// Round 10
// 531.668 us; speedup vs baseline: 1.7182x; 1.7182x over previous
//
#include <hip/hip_runtime.h>
#include <stdint.h>

typedef unsigned short u16;
typedef unsigned int u32;
typedef float f32x4 __attribute__((ext_vector_type(4)));
typedef __bf16 bf16x8 __attribute__((ext_vector_type(8)));
typedef u16 u16x8 __attribute__((ext_vector_type(8)));
typedef u16 u16x4 __attribute__((ext_vector_type(4)));

// Problem geometry (fixed)
#define NB   4
#define SEQ  2048
#define EMB  1024
#define NH   16
#define HDIM 64

#define QSCALE 0.18033688011112042f   // log2(e)/8, folded into qp at projection

__device__ __forceinline__ f32x4 mfma16(bf16x8 a, bf16x8 b, f32x4 c) {
  return __builtin_amdgcn_mfma_f32_16x16x32_bf16(a, b, c, 0, 0, 0);
}
__device__ __forceinline__ u16 f2bf(float f) {
  u32 u = __builtin_bit_cast(u32, f);
  u += 0x7FFFu + ((u >> 16) & 1u);      // round-to-nearest-even
  return (u16)(u >> 16);
}
__device__ __forceinline__ u32 pk2bf(float lo, float hi) {
  return (u32)f2bf(lo) | ((u32)f2bf(hi) << 16);
}
__device__ __forceinline__ float bf2f(u16 h) {
  return __builtin_bit_cast(float, (u32)h << 16);
}
__device__ __forceinline__ bf16x8 ldg8(const u16* p) {
  return *reinterpret_cast<const bf16x8*>(p);
}

// ---------------- prep: fp32->bf16 cvt (y=0..5) + mask bitpack (y=6) ----------------
__global__ __launch_bounds__(256) void prep_kernel(
    const float* __restrict__ q, const float* __restrict__ k, const float* __restrict__ v,
    const float* __restrict__ Wk, const float* __restrict__ Wv, const float* __restrict__ Wo,
    const int* __restrict__ mask,
    u16* __restrict__ qb, u16* __restrict__ kb, u16* __restrict__ vb,
    u16* __restrict__ Wkb, u16* __restrict__ Wvb, u16* __restrict__ Wob,
    u32* __restrict__ bits) {
  const int y = blockIdx.y;
  if (y == 6) {
    const int idx = blockIdx.x * 256 + threadIdx.x;
    if (idx >= NB * SEQ * 64) return;
    const int w = idx & 63;
    const size_t rowbase = (size_t)(idx >> 6) * SEQ;
    const int4* p = reinterpret_cast<const int4*>(mask + rowbase + w * 32);
    u32 m = 0;
#pragma unroll
    for (int j = 0; j < 8; ++j) {
      int4 v4 = p[j];
      m |= (v4.x != 0 ? 1u : 0u) << (j * 4 + 0);
      m |= (v4.y != 0 ? 1u : 0u) << (j * 4 + 1);
      m |= (v4.z != 0 ? 1u : 0u) << (j * 4 + 2);
      m |= (v4.w != 0 ? 1u : 0u) << (j * 4 + 3);
    }
    bits[idx] = m;
    return;
  }
  const float* src; u16* dst; int n8;
  switch (y) {
    case 0: src = q;  dst = qb;  n8 = NB * SEQ * EMB / 8; break;
    case 1: src = k;  dst = kb;  n8 = NB * SEQ * EMB / 8; break;
    case 2: src = v;  dst = vb;  n8 = NB * SEQ * EMB / 8; break;
    case 3: src = Wk; dst = Wkb; n8 = EMB * EMB / 8; break;
    case 4: src = Wv; dst = Wvb; n8 = EMB * EMB / 8; break;
    default: src = Wo; dst = Wob; n8 = EMB * EMB / 8; break;
  }
  int i = blockIdx.x * 256 + threadIdx.x;
  if (i >= n8) return;
  const float4* s = reinterpret_cast<const float4*>(src) + (size_t)i * 2;
  float4 a = s[0], b = s[1];
  u16x8 o;
  o[0] = f2bf(a.x); o[1] = f2bf(a.y); o[2] = f2bf(a.z); o[3] = f2bf(a.w);
  o[4] = f2bf(b.x); o[5] = f2bf(b.y); o[6] = f2bf(b.z); o[7] = f2bf(b.w);
  reinterpret_cast<u16x8*>(dst)[i] = o;
}

// per (b, 64-row qtile, 64-col ktile): 1 if fully unmasked
__global__ __launch_bounds__(256) void tileok_kernel(const u32* __restrict__ bits,
                                                     unsigned char* __restrict__ tok) {
  const int idx = blockIdx.x * 256 + threadIdx.x;      // < 4*32*32
  const int b = idx >> 10, qt = (idx >> 5) & 31, kt = idx & 31;
  const u32* bb = bits + (size_t)b * SEQ * 64;
  u32 acc = 0xFFFFFFFFu;
  for (int rr = 0; rr < 64; ++rr) {
    const u32* pr = bb + (size_t)(qt * 64 + rr) * 64 + kt * 2;
    acc &= pr[0] & pr[1];
  }
  tok[idx] = (acc == 0xFFFFFFFFu) ? 1 : 0;
}

// ---------------- 128x128x(K=1024) bf16 GEMM mainloop (m97 structure) ----------------
__device__ __forceinline__ void gemm_tile(const u16* __restrict__ A,
                                          const u16* __restrict__ W,
                                          int brow, int bcol, int tid,
                                          u16* As, u16* Bs, f32x4 acc[4][4]) {
  const int K = 1024;
  const int l = tid & 63, wv = tid >> 6;
  const int lr = l & 15, lg = l >> 4;
  const int wr = wv >> 1, wc = wv & 1;
  const int srow = l >> 3;
  const int skb = (l & 7) * 16;

  for (int k0 = 0; k0 < K; k0 += 64) {
#pragma unroll
    for (int r = 0; r < 4; ++r) {
      const int chunk = r * 4 + wv;
      const int row = chunk * 8 + srow;
      const char* ga = (const char*)A + ((size_t)(brow + row) * K + k0) * 2 + skb;
      const char* gb = (const char*)W + ((size_t)(bcol + row) * K + k0) * 2 + skb;
      __builtin_amdgcn_global_load_lds(
          (const __attribute__((address_space(1))) u32*)ga,
          (__attribute__((address_space(3))) u32*)((char*)As + chunk * 1024), 16, 0, 0);
      __builtin_amdgcn_global_load_lds(
          (const __attribute__((address_space(1))) u32*)gb,
          (__attribute__((address_space(3))) u32*)((char*)Bs + chunk * 1024), 16, 0, 0);
    }
    __syncthreads();
#pragma unroll
    for (int ks = 0; ks < 2; ++ks) {
      bf16x8 af[4], bfr[4];
#pragma unroll
      for (int m = 0; m < 4; ++m)
        af[m] = *reinterpret_cast<const bf16x8*>(
            (const char*)As + (wr * 64 + m * 16 + lr) * 128 + ks * 64 + lg * 16);
#pragma unroll
      for (int n = 0; n < 4; ++n)
        bfr[n] = *reinterpret_cast<const bf16x8*>(
            (const char*)Bs + (wc * 64 + n * 16 + lr) * 128 + ks * 64 + lg * 16);
#pragma unroll
      for (int m = 0; m < 4; ++m)
#pragma unroll
        for (int n = 0; n < 4; ++n)
          acc[m][n] = mfma16(af[m], bfr[n], acc[m][n]);
    }
    __syncthreads();
  }
}

// z=0: qp = (q@Wv^T+bv)*QSCALE  [B][H][S][HD]
// z=1: kp = k@Wk^T+bk           [B][H][S][HD]
// z=2: vpT = v@Wv^T+bv          [B][H][HD][S] (transposed via LDS)
__global__ __launch_bounds__(256) void proj_gemm(
    const u16* __restrict__ qb, const u16* __restrict__ kb, const u16* __restrict__ vb,
    const u16* __restrict__ Wvb, const u16* __restrict__ Wkb,
    const float* __restrict__ bv, const float* __restrict__ bkp,
    u16* __restrict__ qp, u16* __restrict__ kp, u16* __restrict__ vpT) {
  __shared__ __align__(16) u32 smem_u32[8192];
  u16* As = (u16*)smem_u32;
  u16* Bs = As + 128 * 64;
  const int z = blockIdx.z;
  const u16* A = (z == 0) ? qb : (z == 1) ? kb : vb;
  const u16* W = (z == 1) ? Wkb : Wvb;
  const float* bias = (z == 1) ? bkp : bv;
  const int brow = blockIdx.y * 128;
  const int bcol = blockIdx.x * 128;
  const int tid = threadIdx.x;
  f32x4 acc[4][4] = {};
  gemm_tile(A, W, brow, bcol, tid, As, Bs, acc);
  const int l = tid & 63, wv = tid >> 6;
  const int lr = l & 15, lg = l >> 4;
  const int wr = wv >> 1, wc = wv & 1;

  if (z == 2) {
#pragma unroll
    for (int m = 0; m < 4; ++m)
#pragma unroll
      for (int n = 0; n < 4; ++n) {
        const int cl = wc * 64 + n * 16 + lr;
        const float b0 = bias[bcol + cl];
        const u32 w0 = pk2bf(acc[m][n][0] + b0, acc[m][n][1] + b0);
        const u32 w1 = pk2bf(acc[m][n][2] + b0, acc[m][n][3] + b0);
        const int rp0 = wr * 32 + m * 8 + lg * 2;
        const int a32 = cl * 64 + (rp0 ^ ((lr & 7) << 2));
        uint2 wv2; wv2.x = w0; wv2.y = w1;
        *reinterpret_cast<uint2*>(&smem_u32[a32]) = wv2;
      }
    __syncthreads();
#pragma unroll
    for (int i = 0; i < 8; ++i) {
      const int idx = i * 256 + tid;
      const int cl = idx >> 4;
      const int rp0 = (idx & 15) * 4;
      const int a32 = cl * 64 + (rp0 ^ ((cl & 7) << 2));
      const uint4 d = *reinterpret_cast<const uint4*>(&smem_u32[a32]);
      const int col = bcol + cl, hh = col >> 6, hd = col & 63;
      const int row = brow + rp0 * 2, bb = row >> 11, s = row & 2047;
      *reinterpret_cast<uint4*>(
          vpT + ((((size_t)bb * NH + hh) * HDIM + hd) * SEQ + s)) = d;
    }
  } else {
    u16* dst = (z == 0) ? qp : kp;
    const float sc = (z == 0) ? QSCALE : 1.0f;
#pragma unroll
    for (int m = 0; m < 4; ++m)
#pragma unroll
      for (int n = 0; n < 4; ++n)
#pragma unroll
        for (int r = 0; r < 4; ++r) {
          const int row = brow + wr * 64 + m * 16 + lg * 4 + r;
          const int col = bcol + wc * 64 + n * 16 + lr;
          const float vl = (acc[m][n][r] + bias[col]) * sc;
          const int bb = row >> 11, s = row & 2047, hh = col >> 6, hd = col & 63;
          dst[(((size_t)bb * NH + hh) * SEQ + s) * HDIM + hd] = f2bf(vl);
        }
  }
}

__global__ __launch_bounds__(256) void out_gemm(
    const u16* __restrict__ ctxb, const u16* __restrict__ Wob,
    const float* __restrict__ bo, float* __restrict__ outF) {
  __shared__ __align__(16) u32 smem_u32[8192];
  u16* As = (u16*)smem_u32;
  u16* Bs = As + 128 * 64;
  const int brow = blockIdx.y * 128;
  const int bcol = blockIdx.x * 128;
  const int tid = threadIdx.x;
  f32x4 acc[4][4] = {};
  gemm_tile(ctxb, Wob, brow, bcol, tid, As, Bs, acc);
  const int l = tid & 63, wv = tid >> 6;
  const int lr = l & 15, lg = l >> 4;
  const int wr = wv >> 1, wc = wv & 1;
#pragma unroll
  for (int m = 0; m < 4; ++m)
#pragma unroll
    for (int n = 0; n < 4; ++n)
#pragma unroll
      for (int r = 0; r < 4; ++r) {
        const int row = brow + wr * 64 + m * 16 + lg * 4 + r;
        const int col = bcol + wc * 64 + n * 16 + lr;
        outF[(size_t)row * EMB + col] = acc[m][n][r] + bo[col];
      }
}

// ---------------- fused attention: 32 q-rows/wave, two-pass, barrier-free ----------------
// 1024 blocks x 4 waves; wave = 32 q-rows of one (b,h), full K=2048 (R2's
// measured-best arithmetic intensity: K/V logical reads 3.1 GB vs R9's 6.3 GB).
// XCD swizzle (R2): swz=(bid&7)*128+(bid>>3); Wn=swz*4+wid; qt=Wn&63.
// Pass 1: QK MFMA -> exp2 -> rowsums (registers only).
// Pass 2 per 64-col tile: K loads -> scores -> pn=exp2(s)*rinv -> pbuf bf16
//   (swizzled) -> V loads (bk8 dead first; not co-live) -> PV MFMA ->
//   8x f32x4 NONTEMPORAL stores from pbuf (1KB/instr; nt keeps streaming attn
//   out of L2 so the 8 K/V panels per XCD [4MB] stay resident).
// pbuf wave-private; NO __syncthreads anywhere.
__global__ __launch_bounds__(256) void attn_kernel(
    const u16* __restrict__ qp, const u16* __restrict__ kp, const u16* __restrict__ vpT,
    const u32* __restrict__ bits, const unsigned char* __restrict__ tok,
    float* __restrict__ attn, u16* __restrict__ ctxb) {
  __shared__ __align__(16) u16 pbuf[4][32][64];        // wave-private [wid], 16 KB
  const int tid = threadIdx.x;
  const int l = tid & 63, wid = tid >> 6;
  const int lr = l & 15, lg = l >> 4;
  const int bid = blockIdx.x;
  const int swz = (bid & 7) * 128 + (bid >> 3);
  const int Wn = swz * 4 + wid;                        // 0..4095
  const int qt = Wn & 63, h = (Wn >> 6) & 15, b = Wn >> 10;
  const int q0 = qt * 32;
  const size_t bh = (size_t)b * NH + h;
  const u16* qpb = qp + bh * (SEQ * HDIM);
  const u16* kpb = kp + bh * (SEQ * HDIM);
  const u16* vpb = vpT + bh * (HDIM * SEQ);
  float* attb = attn + bh * ((size_t)SEQ * SEQ);
  const unsigned char* tokb = tok + ((size_t)b * 32 + (qt >> 1)) * 32;
  const u32* bitsb = bits + (size_t)b * SEQ * 64;

  // Q fragments: rows q0 + g*16 + lr, k-dim d*32 + lg*8
  bf16x8 aq[2][2];
#pragma unroll
  for (int g = 0; g < 2; ++g)
#pragma unroll
    for (int d = 0; d < 2; ++d)
      aq[g][d] = ldg8(qpb + (size_t)(q0 + g * 16 + lr) * HDIM + d * 32 + lg * 8);

  // ---- pass 1: rowsums ----
  float sums[2][4] = {{0.f, 0.f, 0.f, 0.f}, {0.f, 0.f, 0.f, 0.f}};
  for (int kt = 0; kt < 32; ++kt) {
    const int kc = kt * 64;
    const bool okt = tokb[kt] != 0;
    bf16x8 bk8[4][2];
#pragma unroll
    for (int st = 0; st < 4; ++st)
#pragma unroll
      for (int d = 0; d < 2; ++d)
        bk8[st][d] = ldg8(kpb + (size_t)(kc + st * 16 + lr) * HDIM + d * 32 + lg * 8);
#pragma unroll
    for (int g = 0; g < 2; ++g)
#pragma unroll
      for (int st = 0; st < 4; ++st) {
        f32x4 s = {0.f, 0.f, 0.f, 0.f};
        s = mfma16(aq[g][0], bk8[st][0], s);
        s = mfma16(aq[g][1], bk8[st][1], s);
#pragma unroll
        for (int r = 0; r < 4; ++r) {
          float sc = s[r];
          if (!okt) {
            const int qrow = q0 + g * 16 + lg * 4 + r;
            const int kpos = kc + st * 16 + lr;
            const u32 wb = bitsb[(size_t)qrow * 64 + (kpos >> 5)];
            if (!((wb >> (kpos & 31)) & 1u)) sc = -1e30f;
          }
          sums[g][r] += __builtin_amdgcn_exp2f(sc);
        }
      }
  }
  float rinv[2][4];
#pragma unroll
  for (int g = 0; g < 2; ++g)
#pragma unroll
    for (int r = 0; r < 4; ++r) {
      float vsum = sums[g][r];
      vsum += __shfl_xor(vsum, 1);
      vsum += __shfl_xor(vsum, 2);
      vsum += __shfl_xor(vsum, 4);
      vsum += __shfl_xor(vsum, 8);
      rinv[g][r] = 1.0f / vsum;
    }

  // ---- pass 2 ----
  f32x4 cacc[2][4] = {};
  for (int kt = 0; kt < 32; ++kt) {
    const int kc = kt * 64;
    const bool okt = tokb[kt] != 0;
    bf16x8 bk8[4][2];
#pragma unroll
    for (int st = 0; st < 4; ++st)
#pragma unroll
      for (int d = 0; d < 2; ++d)
        bk8[st][d] = ldg8(kpb + (size_t)(kc + st * 16 + lr) * HDIM + d * 32 + lg * 8);
#pragma unroll
    for (int g = 0; g < 2; ++g)
#pragma unroll
      for (int st = 0; st < 4; ++st) {
        f32x4 s = {0.f, 0.f, 0.f, 0.f};
        s = mfma16(aq[g][0], bk8[st][0], s);
        s = mfma16(aq[g][1], bk8[st][1], s);
#pragma unroll
        for (int r = 0; r < 4; ++r) {
          float sc = s[r];
          if (!okt) {
            const int qrow = q0 + g * 16 + lg * 4 + r;
            const int kpos = kc + st * 16 + lr;
            const u32 wb = bitsb[(size_t)qrow * 64 + (kpos >> 5)];
            if (!((wb >> (kpos & 31)) & 1u)) sc = -1e30f;
          }
          const float pn = __builtin_amdgcn_exp2f(sc) * rinv[g][r];
          const int row = g * 16 + lg * 4 + r;
          const int col = st * 16 + lr;
          pbuf[wid][row][col ^ ((row & 7) << 3)] = f2bf(pn);
        }
      }
    // V loads after scores: bk8 dead -> vf reuses registers (lower peak VGPR)
    bf16x8 vf[4][2];
#pragma unroll
    for (int ds = 0; ds < 4; ++ds)
#pragma unroll
      for (int x = 0; x < 2; ++x)
        vf[ds][x] = ldg8(vpb + (size_t)(ds * 16 + lr) * SEQ + kc + x * 32 + lg * 8);
    // PV: wave-local pbuf readback as A-fragments (normalized bf16)
#pragma unroll
    for (int g = 0; g < 2; ++g)
#pragma unroll
      for (int ks = 0; ks < 2; ++ks) {
        const int prow = g * 16 + lr;
        const int cb = ks * 32 + lg * 8;
        const bf16x8 pa = *reinterpret_cast<const bf16x8*>(
            &pbuf[wid][prow][cb ^ ((prow & 7) << 3)]);
#pragma unroll
        for (int ds = 0; ds < 4; ++ds)
          cacc[g][ds] = mfma16(pa, vf[ds][ks], cacc[g][ds]);
      }
    // vectorized nt attn stores: 8 instrs x 1KB; rows i*4+lg, cols (l&15)*4
#pragma unroll
    for (int i = 0; i < 8; ++i) {
      const int row = i * 4 + lg;
      const int c4 = (l & 15) * 4;
      const u16x4 raw = *reinterpret_cast<const u16x4*>(
          &pbuf[wid][row][c4 ^ ((row & 7) << 3)]);
      f32x4 o;
      o[0] = bf2f(raw[0]); o[1] = bf2f(raw[1]);
      o[2] = bf2f(raw[2]); o[3] = bf2f(raw[3]);
      __builtin_nontemporal_store(
          o, reinterpret_cast<f32x4*>(attb + (size_t)(q0 + row) * SEQ + kc + c4));
    }
  }

  // ctx write: rows q0 + g*16 + lg*4 + r, d-col ds*16+lr
#pragma unroll
  for (int g = 0; g < 2; ++g)
#pragma unroll
    for (int ds = 0; ds < 4; ++ds)
#pragma unroll
      for (int r = 0; r < 4; ++r)
        ctxb[((size_t)b * SEQ + q0 + g * 16 + lg * 4 + r) * EMB + h * HDIM + ds * 16 + lr] =
            f2bf(cacc[g][ds][r]);
}

// ---------------- host launch ----------------
extern "C" void kernel_launch(void* const* d_in, const int* in_sizes, int n_in,
                              void* d_out, int out_size, void* d_ws, size_t ws_size,
                              hipStream_t stream) {
  const float* q   = (const float*)d_in[0];
  const float* k   = (const float*)d_in[1];
  const float* v   = (const float*)d_in[2];
  const int* mask  = (const int*)d_in[3];
  const float* Wk  = (const float*)d_in[4];
  const float* bk  = (const float*)d_in[5];
  const float* Wv  = (const float*)d_in[6];
  const float* bv  = (const float*)d_in[7];
  const float* Wo  = (const float*)d_in[8];
  const float* bo  = (const float*)d_in[9];

  float* outF = (float*)d_out;
  float* attnF = outF + (size_t)NB * SEQ * EMB;

  const size_t MiB = 1024 * 1024;
  char* ws = (char*)d_ws;
  u16* qb   = (u16*)(ws + 0 * MiB);
  u16* kb   = (u16*)(ws + 16 * MiB);
  u16* vb   = (u16*)(ws + 32 * MiB);
  u16* Wvb  = (u16*)(ws + 48 * MiB);
  u16* Wkb  = (u16*)(ws + 50 * MiB);
  u16* Wob  = (u16*)(ws + 52 * MiB);
  u16* qpB  = (u16*)(ws + 54 * MiB);
  u16* kpB  = (u16*)(ws + 70 * MiB);
  u16* vpT  = (u16*)(ws + 86 * MiB);
  u16* ctxb = (u16*)(ws + 102 * MiB);
  u32* bits = (u32*)(ws + 118 * MiB);
  unsigned char* tok = (unsigned char*)(ws + 120 * MiB);

  prep_kernel<<<dim3(NB * SEQ * EMB / 8 / 256, 7), 256, 0, stream>>>(
      q, k, v, Wk, Wv, Wo, mask, qb, kb, vb, Wkb, Wvb, Wob, bits);

  tileok_kernel<<<NB * 32 * 32 / 256, 256, 0, stream>>>(bits, tok);

  proj_gemm<<<dim3(EMB / 128, NB * SEQ / 128, 3), 256, 0, stream>>>(
      qb, kb, vb, Wvb, Wkb, bv, bk, qpB, kpB, vpT);

  attn_kernel<<<1024, 256, 0, stream>>>(
      qpB, kpB, vpT, bits, tok, attnF, ctxb);

  out_gemm<<<dim3(EMB / 128, NB * SEQ / 128), 256, 0, stream>>>(ctxb, Wob, bo, outF);
}